// Round 15
// baseline (1148.906 us; speedup 1.0000x reference)
//
#include <hip/hip_runtime.h>
#include <cstddef>
#include <cstdint>

// Problem constants: M,B,L,S,Q = 2,64,512,26,512
#define M_ 2
#define B_ 64
#define L_ 512
#define S_ 26
#define Q_ 512
#define NW 4                    // waves per block
#define NT 256                  // threads per block
#define NTQ 8                   // 16-col tiles per wave (128 cols/wave)
#define LB 16
#define TSCALE 256.0f           // trans fp8 scale
#define ETS (1.0f / 256.0f)     // folded into packed emit: cancels TSCALE each step
#define LN2F 0.6931471805599453f

typedef float f32x4 __attribute__((ext_vector_type(4)));
typedef short bfrag8 __attribute__((ext_vector_type(8)));               // 8 bf16
typedef unsigned long long u64x2 __attribute__((ext_vector_type(2)));   // 16B LDS read

// workgroup barrier WITHOUT the vmcnt(0) drain __syncthreads carries.
#define BARRIER() asm volatile("s_waitcnt lgkmcnt(0)\n\ts_barrier" ::: "memory")

// ---- DPP helpers ----
template <int CTRL>
__device__ __forceinline__ float dpp_add(float v) {
    int x = __builtin_amdgcn_update_dpp(0, __builtin_bit_cast(int, v), CTRL, 0xF, 0xF, true);
    return v + __builtin_bit_cast(float, x);
}
__device__ __forceinline__ float red16(float v) {
    v = dpp_add<0xB1>(v);   // lane^1
    v = dpp_add<0x4E>(v);   // lane^2
    v = dpp_add<0x141>(v);  // row_half_mirror (quad^1)
    v = dpp_add<0x140>(v);  // row_mirror      (quad^3)
    return v;
}

// ---- encoders ----
__device__ __forceinline__ uint32_t enc_e4m3(float f) {
    if (!(f > 0.f)) return 0u;
    float v = fminf(f, 448.f);
    if (v < 0.015625f) return (uint32_t)rintf(v * 512.f);
    uint32_t u = __float_as_uint(v);
    u += 0x7FFFFu + ((u >> 20) & 1u);
    uint32_t e2  = ((u >> 23) & 0xffu) - 120u;
    uint32_t man = (u >> 20) & 7u;
    if (e2 > 15u || (e2 == 15u && man > 6u)) return 0x7Eu;
    return (e2 << 3) | man;
}
__device__ __forceinline__ uint32_t enc_bf16(float f) {
    uint32_t u = __float_as_uint(f);
    u += 0x7fffu + ((u >> 16) & 1u);      // RNE
    return u >> 16;
}

// ---- prep 1: trans*256 -> fp8 B-fragments, PERMUTED k-axis ----
// ps = wp*128 + cq*8 + ntq  <->  s = wp*128 + ntq*16 + cq   (wp=0..3, cq=0..15, ntq=0..7)
__global__ void pack_trans_frag(const float* __restrict__ trans,
                                unsigned long long* __restrict__ Bf) {
    int idx  = blockIdx.x * blockDim.x + threadIdx.x;  // M*4*8*16*64 = 65536
    int lane = idx & 63;
    int kt   = (idx >> 6) & 15;
    int nt   = (idx >> 10) & 7;
    int wave = (idx >> 13) & 3;
    int m    = idx >> 15;
    int col  = wave * 128 + nt * 16 + (lane & 15);
    const float* tm = trans + (size_t)m * Q_ * Q_;
    unsigned long long v = 0;
#pragma unroll
    for (int b = 0; b < 8; ++b) {
        int ps = kt * 32 + (lane >> 4) * 8 + b;
        int s  = (ps & ~127) + (ps & 7) * 16 + ((ps >> 3) & 15);  // un-permute
        unsigned long long q = enc_e4m3(tm[(size_t)s * Q_ + col] * TSCALE);
        v |= q << (8 * b);
    }
    Bf[idx] = v;
}

// ---- prep 2: emit*ETS -> bf16 B-fragments (K=32, s>=26 zero) ----
__global__ void pack_emit_frag(const float* __restrict__ emit, uint4* __restrict__ Ef) {
    int idx  = blockIdx.x * blockDim.x + threadIdx.x;  // M*4*8*64 = 4096
    int lane = idx & 63;
    int nt   = (idx >> 6) & 7;
    int wave = (idx >> 9) & 3;
    int m    = idx >> 11;
    int col  = wave * 128 + nt * 16 + (lane & 15);
    int s0   = (lane >> 4) * 8;
    uint32_t h[8];
#pragma unroll
    for (int i = 0; i < 8; ++i) {
        int s = s0 + i;
        h[i] = (s < S_) ? enc_bf16(emit[((size_t)m * S_ + s) * Q_ + col] * ETS) : 0u;
    }
    Ef[idx] = make_uint4(h[0] | (h[1] << 16), h[2] | (h[3] << 16),
                         h[4] | (h[5] << 16), h[6] | (h[7] << 16));
}

// ---- prep 3: inputs -> bf16 A-fragments per (block,t) ----
__global__ void pack_inputs_frag(const float* __restrict__ inputs, uint4* __restrict__ Af) {
    int idx  = blockIdx.x * blockDim.x + threadIdx.x;  // M*4*512*64 = 262144
    int lane = idx & 63;
    int t    = (idx >> 6) & 511;
    int bg   = (idx >> 15) & 3;
    int m    = idx >> 17;
    int colq = lane & 15, krow = lane >> 4;
    int b    = bg * 16 + colq;
    int k0   = krow * 8;
    const float* ip = inputs + ((size_t)(m * B_ + b) * L_ + t) * S_ + k0;
    uint32_t h[8];
#pragma unroll
    for (int i = 0; i < 8; ++i)
        h[i] = (k0 + i < S_) ? enc_bf16(ip[i]) : 0u;
    Af[((size_t)(m * 4 + bg) * L_ + t) * 64 + lane] =
        make_uint4(h[0] | (h[1] << 16), h[2] | (h[3] << 16),
                   h[4] | (h[5] << 16), h[6] | (h[7] << 16));
}

// ---- main: fp8 MFMA recursion + fused bf16 emission MFMA, 4 waves ----
// alpha LDS layout (per 16-row buffer, 512B/row) — identical to R12:
//   chunk q = ps>>3 (8B), q = kt*4 + krw  ->  u = (kt>>1)*8 + krw*2 + (kt&1)
//   byte(row, u, word8) = row*512 + (((u>>1) ^ (row&7))<<4) + (u&1)*8
// Read (lane colq,krow), j=0..7: b128 at colq*512 + (((j*4+krow)^(colq&7))<<4)
//   -> af[2j], af[2j+1].  Write: ps base = wave*128+colq*8 -> ONE u64 per row.
__global__ __launch_bounds__(NT, 1) void hmm_fwd_mfma(
    const float* __restrict__ init_dist,
    const unsigned long long* __restrict__ Bf,
    const uint4* __restrict__ Ef,
    const uint4* __restrict__ Af,
    float* __restrict__ out)
{
    __shared__ char alpha8[2][16 * Q_];
    __shared__ char wsB[2][NW * 4 * 16];   // [buf][wave][krow] : f32x4

    const int tid  = threadIdx.x;
    const int wave = tid >> 6;             // 0..3
    const int lane = tid & 63;
    const int colq = lane & 15;
    const int krow = lane >> 4;
    const int bid  = blockIdx.x;           // 0..7
    const int m    = bid >> 2;
    const int b0   = (bid & 3) * 16;

    // B fragments (trans, fp8): 128 x u64 = 256 VGPRs (unified VGPR/AGPR file)
    unsigned long long bf[NTQ][16];
    {
        const unsigned long long* bp = Bf + (((size_t)m * NW + wave) * NTQ * 16) * 64 + lane;
#pragma unroll
        for (int nt = 0; nt < NTQ; ++nt)
#pragma unroll
            for (int kt = 0; kt < 16; ++kt)
                bf[nt][kt] = bp[(size_t)(nt * 16 + kt) * 64];
#pragma unroll
        for (int nt = 0; nt < NTQ; ++nt)
#pragma unroll
            for (int kt = 0; kt < 16; ++kt)
                asm volatile("" : "+v"(bf[nt][kt]));
    }
    // emit B fragments (bf16)
    bfrag8 ef[NTQ];
#pragma unroll
    for (int nt = 0; nt < NTQ; ++nt)
        ef[nt] = __builtin_bit_cast(bfrag8,
            Ef[(((size_t)m * NW + wave) * NTQ + nt) * 64 + lane]);

    const uint4* ab = Af + ((size_t)bid * L_) * 64 + lane;   // +64 per t

    float* ebase  = out + (size_t)(m * B_ + b0) * L_ * Q_;   // [row][t][col]
    float* ll_out = out + (size_t)M_ * B_ * L_ * Q_;

    float* rp[4];
#pragma unroll
    for (int r = 0; r < 4; ++r)
        rp[r] = ebase + (size_t)(krow * 4 + r) * (L_ * Q_) + wave * 128 + colq;

    // alpha write offsets: ONE u64 per row r at chunk q = wave*16 + colq
    int woff[4];
    {
        const int q   = wave * 16 + colq;
        const int ktw = q >> 2, krww = q & 3;
        const int u   = (ktw >> 1) * 8 + krww * 2 + (ktw & 1);
#pragma unroll
        for (int r = 0; r < 4; ++r) {
            int row = krow * 4 + r;
            woff[r] = row * 512 + ((((u >> 1) ^ (row & 7))) << 4) + (u & 1) * 8;
        }
    }
    int roff[8];
#pragma unroll
    for (int j = 0; j < 8; ++j)
        roff[j] = colq * 512 + (((j * 4 + krow) ^ (colq & 7)) << 4);

    const int wroff = ((colq & 3) * 4 + krow) * 16;   // read wave colq&3's partial
    const int wwoff = (wave * 4 + krow) * 16;

    float a[NTQ][4];
    int   llE[4];
    int   Eprev[4];

    // ================= t = 0 =================
    uint4 ain = ab[0];
    {
        bfrag8 av = __builtin_bit_cast(bfrag8, ain);
        f32x4 ce[NTQ];
#pragma unroll
        for (int nt = 0; nt < NTQ; ++nt) {
            ce[nt] = f32x4{0, 0, 0, 0};
            ce[nt] = __builtin_amdgcn_mfma_f32_16x16x32_bf16(av, ef[nt], ce[nt], 0, 0, 0);
        }
#pragma unroll
        for (int nt = 0; nt < NTQ; ++nt) {
            float iv = init_dist[m * Q_ + wave * 128 + nt * 16 + colq];
#pragma unroll
            for (int r = 0; r < 4; ++r)
                a[nt][r] = iv * ce[nt][r];
        }
        float p[4];
#pragma unroll
        for (int r = 0; r < 4; ++r) {
            float s = 0.f;
#pragma unroll
            for (int nt = 0; nt < NTQ; ++nt) s += a[nt][r];
            p[r] = red16(s);
        }
        if (colq == 0) *(f32x4*)(wsB[0] + wwoff) = f32x4{p[0], p[1], p[2], p[3]};
        __syncthreads();
        f32x4 sv = *(const f32x4*)(wsB[0] + wroff);
#pragma unroll
        for (int r = 0; r < 4; ++r) {
            float shat = red16(sv[r]) * 0.25f;     // 4 copies of 4-wave sum
            int D = (int)((__float_as_uint(shat) >> 23) & 0xffu) - 127;
            int E = D - 11;
            llE[r] = E; Eprev[r] = E;
            float kf = __uint_as_float((uint32_t)(127 - E) << 23);
            uint32_t lo = __builtin_amdgcn_cvt_pk_fp8_f32(
                fminf(a[0][r] * kf, 448.f), fminf(a[1][r] * kf, 448.f), 0, false);
            lo = __builtin_amdgcn_cvt_pk_fp8_f32(
                fminf(a[2][r] * kf, 448.f), fminf(a[3][r] * kf, 448.f), lo, true);
            uint32_t hi = __builtin_amdgcn_cvt_pk_fp8_f32(
                fminf(a[4][r] * kf, 448.f), fminf(a[5][r] * kf, 448.f), 0, false);
            hi = __builtin_amdgcn_cvt_pk_fp8_f32(
                fminf(a[6][r] * kf, 448.f), fminf(a[7][r] * kf, 448.f), hi, true);
            unsigned long long pk = (unsigned long long)lo | ((unsigned long long)hi << 32);
            *(unsigned long long*)(&alpha8[0][woff[r]]) = pk;
        }
        __syncthreads();
    }
    uint4 ain_next = ab[64];   // t = 1

    // ================= t = 1 .. L-1 : ONE lgkm-only barrier per step ============
    for (int t = 1; t < L_; ++t) {
        const int pb = (t - 1) & 1, qb = t & 1;

        ain = ain_next;
        int tn = (t + 1 < L_) ? (t + 1) : t;
        ain_next = ab[(size_t)tn * 64];            // stays in flight across barrier

        // shadow: previous step's true row-sum -> inv, E, kf
        f32x4 sv = *(const f32x4*)(wsB[pb] + wroff);
        float inv[4], kf[4];
        int Ecur[4];
#pragma unroll
        for (int r = 0; r < 4; ++r) {
            float shat = red16(sv[r]) * 0.25f;
            inv[r] = __builtin_amdgcn_rcpf(shat);
            int D = (int)((__float_as_uint(shat) >> 23) & 0xffu) - 127;
            Ecur[r] = D - Eprev[r] - 12;
            kf[r] = __uint_as_float((uint32_t)(127 - Ecur[r]) << 23);
        }

        // deferred normalized store of forward_{t-1} (vmcnt, flies across barriers)
#pragma unroll
        for (int r = 0; r < 4; ++r) rp[r] += Q_;
#pragma unroll
        for (int nt = 0; nt < NTQ; ++nt)
#pragma unroll
            for (int r = 0; r < 4; ++r)
                rp[r][nt * 16 - Q_] = a[nt][r] * inv[r];

        // MFMA block: 8 b128 af reads, 8 bf16 chains + 8 fp8 chains
        bfrag8 av = __builtin_bit_cast(bfrag8, ain);
        f32x4 c[NTQ], ce[NTQ];
#pragma unroll
        for (int nt = 0; nt < NTQ; ++nt) { c[nt] = f32x4{0,0,0,0}; ce[nt] = f32x4{0,0,0,0}; }
        __builtin_amdgcn_s_setprio(1);
#pragma unroll
        for (int j = 0; j < 8; ++j) {
            u64x2 aq = *(const u64x2*)(&alpha8[pb][roff[j]]);
            ce[j] = __builtin_amdgcn_mfma_f32_16x16x32_bf16(av, ef[j], ce[j], 0, 0, 0);
#pragma unroll
            for (int nt = 0; nt < NTQ; ++nt)
                c[nt] = __builtin_amdgcn_mfma_f32_16x16x32_fp8_fp8(
                            (long)aq.x, (long)bf[nt][2 * j], c[nt], 0, 0, 0);
#pragma unroll
            for (int nt = 0; nt < NTQ; ++nt)
                c[nt] = __builtin_amdgcn_mfma_f32_16x16x32_fp8_fp8(
                            (long)aq.y, (long)bf[nt][2 * j + 1], c[nt], 0, 0, 0);
        }
        __builtin_amdgcn_s_setprio(0);

        // â_t = ĉ · ê_t ; quantize+write alpha FIRST (LDS write drains under red16)
#pragma unroll
        for (int nt = 0; nt < NTQ; ++nt)
#pragma unroll
            for (int r = 0; r < 4; ++r)
                a[nt][r] = c[nt][r] * ce[nt][r];

        if (t < L_ - 1) {
#pragma unroll
            for (int r = 0; r < 4; ++r) {
                llE[r] += Ecur[r]; Eprev[r] = Ecur[r];
                float k = kf[r];
                uint32_t lo = __builtin_amdgcn_cvt_pk_fp8_f32(
                    fminf(a[0][r] * k, 448.f), fminf(a[1][r] * k, 448.f), 0, false);
                lo = __builtin_amdgcn_cvt_pk_fp8_f32(
                    fminf(a[2][r] * k, 448.f), fminf(a[3][r] * k, 448.f), lo, true);
                uint32_t hi = __builtin_amdgcn_cvt_pk_fp8_f32(
                    fminf(a[4][r] * k, 448.f), fminf(a[5][r] * k, 448.f), 0, false);
                hi = __builtin_amdgcn_cvt_pk_fp8_f32(
                    fminf(a[6][r] * k, 448.f), fminf(a[7][r] * k, 448.f), hi, true);
                unsigned long long pk = (unsigned long long)lo | ((unsigned long long)hi << 32);
                *(unsigned long long*)(&alpha8[qb][woff[r]]) = pk;
            }
        }

        // wave-partial row sums
        float p[4];
#pragma unroll
        for (int r = 0; r < 4; ++r) {
            float s = 0.f;
#pragma unroll
            for (int nt = 0; nt < NTQ; ++nt) s += a[nt][r];
            p[r] = red16(s);
        }
        if (colq == 0) *(f32x4*)(wsB[qb] + wwoff) = f32x4{p[0], p[1], p[2], p[3]};

        BARRIER();
    }

    // ================= final: normalize t = L-1, write ll =================
    {
        f32x4 sv = *(const f32x4*)(wsB[(L_ - 1) & 1] + wroff);
        float ll[4];
#pragma unroll
        for (int r = 0; r < 4; ++r) {
            float shat = red16(sv[r]) * 0.25f;
            float invr = __builtin_amdgcn_rcpf(shat);
#pragma unroll
            for (int nt = 0; nt < NTQ; ++nt)
                rp[r][nt * 16] = a[nt][r] * invr;
            ll[r] = LN2F * (8.0f + __log2f(shat) + (float)llE[r]);
        }
        if (wave == 0 && colq == 0) {
#pragma unroll
            for (int r = 0; r < 4; ++r)
                ll_out[m * B_ + b0 + krow * 4 + r] = ll[r];
        }
    }
}

// ---- fallback path (insufficient workspace): emission prekernel + fp32 recursion ----
__global__ __launch_bounds__(512) void emission_kernel(
    const float* __restrict__ inputs, const float* __restrict__ emit,
    float* __restrict__ out) {
    __shared__ float ein[LB * S_];
    const int tid = threadIdx.x;
    const int lt  = blockIdx.x % (L_ / LB);
    const int mb  = blockIdx.x / (L_ / LB);
    const int m   = mb / B_;
    const int b   = mb % B_;
    const int k   = tid;
    const float* inrow = inputs + ((size_t)(m * B_ + b) * L_ + (size_t)lt * LB) * S_;
    if (tid < LB * S_) ein[tid] = inrow[tid];
    float emv[S_];
    const float* em = emit + (size_t)m * S_ * Q_ + k;
#pragma unroll
    for (int s = 0; s < S_; ++s) emv[s] = em[(size_t)s * Q_];
    __syncthreads();
    float* orow = out + ((size_t)(m * B_ + b) * L_ + (size_t)lt * LB) * Q_ + k;
#pragma unroll
    for (int il = 0; il < LB; ++il) {
        float e = 0.f;
#pragma unroll
        for (int s = 0; s < S_; ++s) e = fmaf(ein[il * S_ + s], emv[s], e);
        orow[(size_t)il * Q_] = e;
    }
}

__global__ __launch_bounds__(512, 1) void hmm_fwd_f32(
    const float* __restrict__ init_dist,
    const float* __restrict__ trans,
    float* __restrict__ out)
{
    __shared__ float alphaF[Q_];
    __shared__ alignas(16) float apart[4][Q_];
    __shared__ float wred[8];
    const int tid  = threadIdx.x;
    const int m    = blockIdx.x / B_;
    const int b    = blockIdx.x % B_;
    const int k    = tid;
    const int k0   = (tid & 127) * 4;
    const int qh   = tid >> 7;
    const int lane = tid & 63;
    const int wav  = tid >> 6;
    float* erow   = out + (size_t)(m * B_ + b) * L_ * Q_;
    float* ll_out = out + (size_t)M_ * B_ * L_ * Q_;
    float ll = 0.f;
    {
        float e = erow[k];
        float a = init_dist[m * Q_ + k] * e;
        float r = a;
#pragma unroll
        for (int off = 32; off; off >>= 1) r += __shfl_xor(r, off, 64);
        if (lane == 0) wred[wav] = r;
        __syncthreads();
        float s = 0.f;
#pragma unroll
        for (int w = 0; w < 8; ++w) s += wred[w];
        ll = logf(s);
        float n = a * (1.0f / s);
        alphaF[k] = n;
        erow[k] = n;
        __syncthreads();
    }
    for (int t = 1; t < L_; ++t) {
        float e = erow[(size_t)t * Q_ + k];
        float4 acc = make_float4(0.f, 0.f, 0.f, 0.f);
        const float* tg = trans + (size_t)m * Q_ * Q_ + (size_t)(qh * 128) * Q_ + k0;
#pragma unroll 4
        for (int q = 0; q < 128; ++q) {
            float4 tv = *(const float4*)(tg + (size_t)q * Q_);
            float aq = alphaF[qh * 128 + q];
            acc.x = fmaf(aq, tv.x, acc.x);
            acc.y = fmaf(aq, tv.y, acc.y);
            acc.z = fmaf(aq, tv.z, acc.z);
            acc.w = fmaf(aq, tv.w, acc.w);
        }
        *(float4*)&apart[qh][k0] = acc;
        __syncthreads();
        float avs = apart[0][k] + apart[1][k] + apart[2][k] + apart[3][k];
        float a   = avs * e;
        float r = a;
#pragma unroll
        for (int off = 32; off; off >>= 1) r += __shfl_xor(r, off, 64);
        if (lane == 0) wred[wav] = r;
        __syncthreads();
        float s = 0.f;
#pragma unroll
        for (int w = 0; w < 8; ++w) s += wred[w];
        ll += logf(s);
        float n = a * (1.0f / s);
        alphaF[k] = n;
        erow[(size_t)t * Q_ + k] = n;
        __syncthreads();
    }
    if (tid == 0) ll_out[m * B_ + b] = ll;
}

extern "C" void kernel_launch(void* const* d_in, const int* in_sizes, int n_in,
                              void* d_out, int out_size, void* d_ws, size_t ws_size,
                              hipStream_t stream) {
    const float* inputs    = (const float*)d_in[0];
    const float* init_dist = (const float*)d_in[1];
    const float* trans     = (const float*)d_in[2];
    const float* emit      = (const float*)d_in[3];
    float* out             = (float*)d_out;

    const size_t bf_bytes = (size_t)M_ * NW * NTQ * 16 * 64 * 8;   // 512 KB
    const size_t ef_bytes = (size_t)M_ * NW * NTQ * 64 * 16;       // 64 KB
    const size_t af_bytes = (size_t)M_ * 4 * L_ * 64 * 16;         // 4 MB
    const bool mfma_path = (ws_size >= bf_bytes + ef_bytes + af_bytes);

    if (mfma_path) {
        unsigned long long* Bf = (unsigned long long*)d_ws;
        uint4* Ef = (uint4*)((char*)d_ws + bf_bytes);
        uint4* Af = (uint4*)((char*)d_ws + bf_bytes + ef_bytes);
        hipLaunchKernelGGL(pack_trans_frag, dim3((M_ * NW * NTQ * 16 * 64) / 256), dim3(256),
                           0, stream, trans, Bf);
        hipLaunchKernelGGL(pack_emit_frag, dim3((M_ * NW * NTQ * 64) / 256), dim3(256),
                           0, stream, emit, Ef);
        hipLaunchKernelGGL(pack_inputs_frag, dim3((M_ * 4 * L_ * 64) / 256), dim3(256),
                           0, stream, inputs, Af);
        hipLaunchKernelGGL(hmm_fwd_mfma, dim3(M_ * B_ / 16), dim3(NT), 0, stream,
                           init_dist, Bf, Ef, Af, out);
    } else {
        hipLaunchKernelGGL(emission_kernel, dim3(M_ * B_ * (L_ / LB)), dim3(512), 0, stream,
                           inputs, emit, out);
        hipLaunchKernelGGL(hmm_fwd_f32, dim3(M_ * B_), dim3(512), 0, stream,
                           init_dist, trans, out);
    }
}

// Round 16
// 733.067 us; speedup vs baseline: 1.5673x; 1.5673x over previous
//
#include <hip/hip_runtime.h>
#include <cstddef>
#include <cstdint>

// Problem constants: M,B,L,S,Q = 2,64,512,26,512
#define M_ 2
#define B_ 64
#define L_ 512
#define S_ 26
#define Q_ 512
#define NT 512
#define LB 16
#define TSCALE 256.0f           // trans fp8 scale
#define ETS (1.0f / 256.0f)     // folded into packed emit: cancels TSCALE each step
#define LN2F 0.6931471805599453f

typedef float f32x4 __attribute__((ext_vector_type(4)));
typedef short bfrag8 __attribute__((ext_vector_type(8)));               // 8 bf16
typedef int   i32x8  __attribute__((ext_vector_type(8)));               // 32B MFMA operand
typedef unsigned long long u64x2 __attribute__((ext_vector_type(2)));   // 16B LDS read

// workgroup barrier WITHOUT the vmcnt(0) drain __syncthreads carries.
#define BARRIER() asm volatile("s_waitcnt lgkmcnt(0)\n\ts_barrier" ::: "memory")

// ---- DPP helpers ----
template <int CTRL>
__device__ __forceinline__ float dpp_add(float v) {
    int x = __builtin_amdgcn_update_dpp(0, __builtin_bit_cast(int, v), CTRL, 0xF, 0xF, true);
    return v + __builtin_bit_cast(float, x);
}
__device__ __forceinline__ float red16(float v) {
    v = dpp_add<0xB1>(v);   // lane^1
    v = dpp_add<0x4E>(v);   // lane^2
    v = dpp_add<0x141>(v);  // row_half_mirror (quad^1)
    v = dpp_add<0x140>(v);  // row_mirror      (quad^3)
    return v;
}

// ---- encoders ----
__device__ __forceinline__ uint32_t enc_e4m3(float f) {
    if (!(f > 0.f)) return 0u;
    float v = fminf(f, 448.f);
    if (v < 0.015625f) return (uint32_t)rintf(v * 512.f);
    uint32_t u = __float_as_uint(v);
    u += 0x7FFFFu + ((u >> 20) & 1u);
    uint32_t e2  = ((u >> 23) & 0xffu) - 120u;
    uint32_t man = (u >> 20) & 7u;
    if (e2 > 15u || (e2 == 15u && man > 6u)) return 0x7Eu;
    return (e2 << 3) | man;
}
__device__ __forceinline__ uint32_t enc_bf16(float f) {
    uint32_t u = __float_as_uint(f);
    u += 0x7fffu + ((u >> 16) & 1u);      // RNE
    return u >> 16;
}

// ---- prep 1: trans*256 -> fp8 B-fragments for 16x16x128 MX MFMA ----
// PERMUTED k-axis: ps = wp*64 + cq*4 + ntq <-> s = wp*64 + ntq*16 + cq.
// Fragment (m,wave,nt,kt): lane holds col = wave*64+nt*16+(lane&15),
// k-byte j (0..31) = ps = kt*128 + (lane>>4)*32 + j.  8 dwords/lane.
__global__ void pack_trans_frag(const float* __restrict__ trans,
                                uint32_t* __restrict__ Bf) {
    int idx  = blockIdx.x * blockDim.x + threadIdx.x;  // M*8*4*4*64 = 16384
    int lane = idx & 63;
    int kt   = (idx >> 6) & 3;
    int nt   = (idx >> 8) & 3;
    int wave = (idx >> 10) & 7;
    int m    = idx >> 13;
    int col  = wave * 64 + nt * 16 + (lane & 15);
    const float* tm = trans + (size_t)m * Q_ * Q_;
    uint32_t w[8];
#pragma unroll
    for (int d = 0; d < 8; ++d) {
        uint32_t v = 0;
#pragma unroll
        for (int b = 0; b < 4; ++b) {
            int j  = d * 4 + b;
            int ps = kt * 128 + (lane >> 4) * 32 + j;
            int s  = (ps & ~63) + (ps & 3) * 16 + ((ps >> 2) & 15);  // un-permute
            v |= enc_e4m3(tm[(size_t)s * Q_ + col] * TSCALE) << (8 * b);
        }
        w[d] = v;
    }
    uint32_t* dst = Bf + (size_t)idx * 8;
    *(uint4*)dst       = make_uint4(w[0], w[1], w[2], w[3]);
    *(uint4*)(dst + 4) = make_uint4(w[4], w[5], w[6], w[7]);
}

// ---- prep 2: emit*ETS -> bf16 B-fragments (K=32, s>=26 zero) ----
__global__ void pack_emit_frag(const float* __restrict__ emit, uint4* __restrict__ Ef) {
    int idx  = blockIdx.x * blockDim.x + threadIdx.x;  // M*8*4*64 = 4096
    int lane = idx & 63;
    int nt   = (idx >> 6) & 3;
    int wave = (idx >> 8) & 7;
    int m    = idx >> 11;
    int col  = wave * 64 + nt * 16 + (lane & 15);
    int s0   = (lane >> 4) * 8;
    uint32_t h[8];
#pragma unroll
    for (int i = 0; i < 8; ++i) {
        int s = s0 + i;
        h[i] = (s < S_) ? enc_bf16(emit[((size_t)m * S_ + s) * Q_ + col] * ETS) : 0u;
    }
    Ef[idx] = make_uint4(h[0] | (h[1] << 16), h[2] | (h[3] << 16),
                         h[4] | (h[5] << 16), h[6] | (h[7] << 16));
}

// ---- prep 3: inputs -> bf16 A-fragments per (block,t) ----
__global__ void pack_inputs_frag(const float* __restrict__ inputs, uint4* __restrict__ Af) {
    int idx  = blockIdx.x * blockDim.x + threadIdx.x;  // M*4*512*64 = 262144
    int lane = idx & 63;
    int t    = (idx >> 6) & 511;
    int bg   = (idx >> 15) & 3;
    int m    = idx >> 17;
    int colq = lane & 15, krow = lane >> 4;
    int b    = bg * 16 + colq;
    int k0   = krow * 8;
    const float* ip = inputs + ((size_t)(m * B_ + b) * L_ + t) * S_ + k0;
    uint32_t h[8];
#pragma unroll
    for (int i = 0; i < 8; ++i)
        h[i] = (k0 + i < S_) ? enc_bf16(ip[i]) : 0u;
    Af[((size_t)(m * 4 + bg) * L_ + t) * 64 + lane] =
        make_uint4(h[0] | (h[1] << 16), h[2] | (h[3] << 16),
                   h[4] | (h[5] << 16), h[6] | (h[7] << 16));
}

// ---- main: MX-scaled fp8 K=128 MFMA recursion + fused bf16 emission MFMA ----
// alpha LDS (16 rows x 512B): 16B slot index = ps>>4 (0..31);
//   byte(row, ps) = row*512 + ((ps>>4) ^ (row&7))*16 + (ps&15).
// Write: thread (wave,colq,krow), r: psbase = wave*64+colq*4, one u32 per row.
// Read (lane arow=lane&15, krw=lane>>4), kt: slots kt*8+krw*2 and +1 -> 2 b128.
__global__ __launch_bounds__(NT, 2) void hmm_fwd_mfma(
    const float* __restrict__ init_dist,
    const uint32_t* __restrict__ Bf,
    const uint4* __restrict__ Ef,
    const uint4* __restrict__ Af,
    float* __restrict__ out)
{
    __shared__ char alpha8[2][16 * Q_];
    __shared__ char wsB[2][8 * 4 * 16];    // [buf][wave][krow] : f32x4

    const int tid  = threadIdx.x;
    const int wave = tid >> 6;
    const int lane = tid & 63;
    const int colq = lane & 15;            // = arow for the A-read
    const int krow = lane >> 4;
    const int bid  = blockIdx.x;           // 0..7
    const int m    = bid >> 2;
    const int b0   = (bid & 3) * 16;

    // B fragments (trans, fp8): 4nt x 4kt x 8 VGPR = 128 regs
    union Bfrag { unsigned long long q[4]; i32x8 v; };
    Bfrag bf[4][4];
    {
        const unsigned long long* bp =
            (const unsigned long long*)Bf + ((size_t)(m * 8 + wave) * 16) * 256 + lane * 4;
#pragma unroll
        for (int nt = 0; nt < 4; ++nt)
#pragma unroll
            for (int kt = 0; kt < 4; ++kt) {
                const unsigned long long* f = bp + (size_t)(nt * 4 + kt) * 256;
#pragma unroll
                for (int h = 0; h < 4; ++h) bf[nt][kt].q[h] = f[h];
            }
#pragma unroll
        for (int nt = 0; nt < 4; ++nt)
#pragma unroll
            for (int kt = 0; kt < 4; ++kt)
#pragma unroll
                for (int h = 0; h < 4; ++h)
                    asm volatile("" : "+v"(bf[nt][kt].q[h]));
    }
    // emit B fragments (bf16)
    bfrag8 ef[4];
#pragma unroll
    for (int nt = 0; nt < 4; ++nt)
        ef[nt] = __builtin_bit_cast(bfrag8,
            Ef[(((size_t)m * 8 + wave) * 4 + nt) * 64 + lane]);

    const uint4* ab = Af + ((size_t)bid * L_) * 64 + lane;   // +64 per t

    float* ebase  = out + (size_t)(m * B_ + b0) * L_ * Q_;   // [row][t][col]
    float* ll_out = out + (size_t)M_ * B_ * L_ * Q_;

    float* rp[4];
#pragma unroll
    for (int r = 0; r < 4; ++r)
        rp[r] = ebase + (size_t)(krow * 4 + r) * (L_ * Q_) + wave * 64 + colq;

    // alpha write offsets: one u32 per row at psbase = wave*64 + colq*4
    int woff[4];
    {
        const int slot = wave * 4 + (colq >> 2);
        const int bis  = (colq & 3) << 2;
#pragma unroll
        for (int r = 0; r < 4; ++r) {
            int row = krow * 4 + r;
            woff[r] = row * 512 + ((slot ^ (row & 7)) << 4) + bis;
        }
    }
    // A-frag read offsets: 2 per kt
    int roff[4][2];
#pragma unroll
    for (int kt = 0; kt < 4; ++kt) {
        int s0 = kt * 8 + krow * 2;
        roff[kt][0] = colq * 512 + ((s0 ^ (colq & 7)) << 4);
        roff[kt][1] = colq * 512 + (((s0 + 1) ^ (colq & 7)) << 4);
    }

    const int wroff = ((colq & 7) * 4 + krow) * 16;
    const int wwoff = (wave * 4 + krow) * 16;

    float a[4][4];
    int   llE[4];
    int   Eprev[4];

    // ================= t = 0 =================
    uint4 ain = ab[0];
    {
        bfrag8 av = __builtin_bit_cast(bfrag8, ain);
        f32x4 ce[4];
#pragma unroll
        for (int nt = 0; nt < 4; ++nt) {
            ce[nt] = f32x4{0, 0, 0, 0};
            ce[nt] = __builtin_amdgcn_mfma_f32_16x16x32_bf16(av, ef[nt], ce[nt], 0, 0, 0);
        }
#pragma unroll
        for (int nt = 0; nt < 4; ++nt) {
            float iv = init_dist[m * Q_ + wave * 64 + nt * 16 + colq];
#pragma unroll
            for (int r = 0; r < 4; ++r)
                a[nt][r] = iv * ce[nt][r];
        }
        float p[4];
#pragma unroll
        for (int r = 0; r < 4; ++r)
            p[r] = red16(a[0][r] + a[1][r] + a[2][r] + a[3][r]);
        if (colq == 0) *(f32x4*)(wsB[0] + wwoff) = f32x4{p[0], p[1], p[2], p[3]};
        __syncthreads();
        f32x4 sv = *(const f32x4*)(wsB[0] + wroff);
#pragma unroll
        for (int r = 0; r < 4; ++r) {
            float shat = red16(sv[r]) * 0.5f;
            int D = (int)((__float_as_uint(shat) >> 23) & 0xffu) - 127;
            int E = D - 11;
            llE[r] = E; Eprev[r] = E;
            float kf = __uint_as_float((uint32_t)(127 - E) << 23);
            uint32_t pk = __builtin_amdgcn_cvt_pk_fp8_f32(
                fminf(a[0][r] * kf, 448.f), fminf(a[1][r] * kf, 448.f), 0, false);
            pk = __builtin_amdgcn_cvt_pk_fp8_f32(
                fminf(a[2][r] * kf, 448.f), fminf(a[3][r] * kf, 448.f), pk, true);
            *(uint32_t*)(&alpha8[0][woff[r]]) = pk;
        }
        __syncthreads();
    }
    uint4 ain_next = ab[64];   // t = 1

    // ================= t = 1 .. L-1 : ONE lgkm-only barrier per step ============
    for (int t = 1; t < L_; ++t) {
        const int pb = (t - 1) & 1, qb = t & 1;

        ain = ain_next;
        int tn = (t + 1 < L_) ? (t + 1) : t;
        ain_next = ab[(size_t)tn * 64];            // stays in flight across barrier

        // shadow: previous step's true row-sum -> inv, E, kf
        f32x4 sv = *(const f32x4*)(wsB[pb] + wroff);
        float inv[4], kf[4];
        int Ecur[4];
#pragma unroll
        for (int r = 0; r < 4; ++r) {
            float shat = red16(sv[r]) * 0.5f;
            inv[r] = __builtin_amdgcn_rcpf(shat);
            int D = (int)((__float_as_uint(shat) >> 23) & 0xffu) - 127;
            Ecur[r] = D - Eprev[r] - 12;
            kf[r] = __uint_as_float((uint32_t)(127 - Ecur[r]) << 23);
        }

        // deferred normalized store of forward_{t-1}
#pragma unroll
        for (int r = 0; r < 4; ++r) rp[r] += Q_;
#pragma unroll
        for (int nt = 0; nt < 4; ++nt)
#pragma unroll
            for (int r = 0; r < 4; ++r)
                rp[r][nt * 16 - Q_] = a[nt][r] * inv[r];

        // MFMA block: 4 kt x (2 b128 A-reads + 4 MX MFMAs) + interleaved e-MFMA
        bfrag8 av = __builtin_bit_cast(bfrag8, ain);
        f32x4 c[4], ce[4];
#pragma unroll
        for (int nt = 0; nt < 4; ++nt) { c[nt] = f32x4{0,0,0,0}; ce[nt] = f32x4{0,0,0,0}; }
        __builtin_amdgcn_s_setprio(1);
#pragma unroll
        for (int kt = 0; kt < 4; ++kt) {
            union Afrag { u64x2 h[2]; i32x8 v; } afr;
            afr.h[0] = *(const u64x2*)(&alpha8[pb][roff[kt][0]]);
            afr.h[1] = *(const u64x2*)(&alpha8[pb][roff[kt][1]]);
            ce[kt] = __builtin_amdgcn_mfma_f32_16x16x32_bf16(av, ef[kt], ce[kt], 0, 0, 0);
#pragma unroll
            for (int nt = 0; nt < 4; ++nt)
                c[nt] = __builtin_amdgcn_mfma_scale_f32_16x16x128_f8f6f4(
                            afr.v, bf[nt][kt].v, c[nt],
                            0, 0,                    // cbsz=fp8, blgp=fp8
                            0, 0x7F7F7F7F,           // scale A = 1.0 (any opsel byte)
                            0, 0x7F7F7F7F);          // scale B = 1.0
        }
        __builtin_amdgcn_s_setprio(0);

        // â_t = ĉ · ê_t ; quantize+write alpha first, then row sums
#pragma unroll
        for (int nt = 0; nt < 4; ++nt)
#pragma unroll
            for (int r = 0; r < 4; ++r)
                a[nt][r] = c[nt][r] * ce[nt][r];

        if (t < L_ - 1) {
#pragma unroll
            for (int r = 0; r < 4; ++r) {
                llE[r] += Ecur[r]; Eprev[r] = Ecur[r];
                float k = kf[r];
                uint32_t pk = __builtin_amdgcn_cvt_pk_fp8_f32(
                    fminf(a[0][r] * k, 448.f), fminf(a[1][r] * k, 448.f), 0, false);
                pk = __builtin_amdgcn_cvt_pk_fp8_f32(
                    fminf(a[2][r] * k, 448.f), fminf(a[3][r] * k, 448.f), pk, true);
                *(uint32_t*)(&alpha8[qb][woff[r]]) = pk;
            }
        }

        float p[4];
#pragma unroll
        for (int r = 0; r < 4; ++r)
            p[r] = red16(a[0][r] + a[1][r] + a[2][r] + a[3][r]);
        if (colq == 0) *(f32x4*)(wsB[qb] + wwoff) = f32x4{p[0], p[1], p[2], p[3]};

        BARRIER();
    }

    // ================= final: normalize t = L-1, write ll =================
    {
        f32x4 sv = *(const f32x4*)(wsB[(L_ - 1) & 1] + wroff);
        float ll[4];
#pragma unroll
        for (int r = 0; r < 4; ++r) {
            float shat = red16(sv[r]) * 0.5f;
            float invr = __builtin_amdgcn_rcpf(shat);
#pragma unroll
            for (int nt = 0; nt < 4; ++nt)
                rp[r][nt * 16] = a[nt][r] * invr;
            ll[r] = LN2F * (8.0f + __log2f(shat) + (float)llE[r]);
        }
        if (wave == 0 && colq == 0) {
#pragma unroll
            for (int r = 0; r < 4; ++r)
                ll_out[m * B_ + b0 + krow * 4 + r] = ll[r];
        }
    }
}

// ---- fallback path (insufficient workspace): emission prekernel + fp32 recursion ----
__global__ __launch_bounds__(512) void emission_kernel(
    const float* __restrict__ inputs, const float* __restrict__ emit,
    float* __restrict__ out) {
    __shared__ float ein[LB * S_];
    const int tid = threadIdx.x;
    const int lt  = blockIdx.x % (L_ / LB);
    const int mb  = blockIdx.x / (L_ / LB);
    const int m   = mb / B_;
    const int b   = mb % B_;
    const int k   = tid;
    const float* inrow = inputs + ((size_t)(m * B_ + b) * L_ + (size_t)lt * LB) * S_;
    if (tid < LB * S_) ein[tid] = inrow[tid];
    float emv[S_];
    const float* em = emit + (size_t)m * S_ * Q_ + k;
#pragma unroll
    for (int s = 0; s < S_; ++s) emv[s] = em[(size_t)s * Q_];
    __syncthreads();
    float* orow = out + ((size_t)(m * B_ + b) * L_ + (size_t)lt * LB) * Q_ + k;
#pragma unroll
    for (int il = 0; il < LB; ++il) {
        float e = 0.f;
#pragma unroll
        for (int s = 0; s < S_; ++s) e = fmaf(ein[il * S_ + s], emv[s], e);
        orow[(size_t)il * Q_] = e;
    }
}

__global__ __launch_bounds__(512, 1) void hmm_fwd_f32(
    const float* __restrict__ init_dist,
    const float* __restrict__ trans,
    float* __restrict__ out)
{
    __shared__ float alphaF[Q_];
    __shared__ alignas(16) float apart[4][Q_];
    __shared__ float wred[8];
    const int tid  = threadIdx.x;
    const int m    = blockIdx.x / B_;
    const int b    = blockIdx.x % B_;
    const int k    = tid;
    const int k0   = (tid & 127) * 4;
    const int qh   = tid >> 7;
    const int lane = tid & 63;
    const int wav  = tid >> 6;
    float* erow   = out + (size_t)(m * B_ + b) * L_ * Q_;
    float* ll_out = out + (size_t)M_ * B_ * L_ * Q_;
    float ll = 0.f;
    {
        float e = erow[k];
        float a = init_dist[m * Q_ + k] * e;
        float r = a;
#pragma unroll
        for (int off = 32; off; off >>= 1) r += __shfl_xor(r, off, 64);
        if (lane == 0) wred[wav] = r;
        __syncthreads();
        float s = 0.f;
#pragma unroll
        for (int w = 0; w < 8; ++w) s += wred[w];
        ll = logf(s);
        float n = a * (1.0f / s);
        alphaF[k] = n;
        erow[k] = n;
        __syncthreads();
    }
    for (int t = 1; t < L_; ++t) {
        float e = erow[(size_t)t * Q_ + k];
        float4 acc = make_float4(0.f, 0.f, 0.f, 0.f);
        const float* tg = trans + (size_t)m * Q_ * Q_ + (size_t)(qh * 128) * Q_ + k0;
#pragma unroll 4
        for (int q = 0; q < 128; ++q) {
            float4 tv = *(const float4*)(tg + (size_t)q * Q_);
            float aq = alphaF[qh * 128 + q];
            acc.x = fmaf(aq, tv.x, acc.x);
            acc.y = fmaf(aq, tv.y, acc.y);
            acc.z = fmaf(aq, tv.z, acc.z);
            acc.w = fmaf(aq, tv.w, acc.w);
        }
        *(float4*)&apart[qh][k0] = acc;
        __syncthreads();
        float avs = apart[0][k] + apart[1][k] + apart[2][k] + apart[3][k];
        float a   = avs * e;
        float r = a;
#pragma unroll
        for (int off = 32; off; off >>= 1) r += __shfl_xor(r, off, 64);
        if (lane == 0) wred[wav] = r;
        __syncthreads();
        float s = 0.f;
#pragma unroll
        for (int w = 0; w < 8; ++w) s += wred[w];
        ll += logf(s);
        float n = a * (1.0f / s);
        alphaF[k] = n;
        erow[(size_t)t * Q_ + k] = n;
        __syncthreads();
    }
    if (tid == 0) ll_out[m * B_ + b] = ll;
}

extern "C" void kernel_launch(void* const* d_in, const int* in_sizes, int n_in,
                              void* d_out, int out_size, void* d_ws, size_t ws_size,
                              hipStream_t stream) {
    const float* inputs    = (const float*)d_in[0];
    const float* init_dist = (const float*)d_in[1];
    const float* trans     = (const float*)d_in[2];
    const float* emit      = (const float*)d_in[3];
    float* out             = (float*)d_out;

    const size_t bf_bytes = (size_t)M_ * 8 * 4 * 4 * 64 * 32;      // 512 KB
    const size_t ef_bytes = (size_t)M_ * 8 * 4 * 64 * 16;          // 64 KB
    const size_t af_bytes = (size_t)M_ * 4 * L_ * 64 * 16;         // 4 MB
    const bool mfma_path = (ws_size >= bf_bytes + ef_bytes + af_bytes);

    if (mfma_path) {
        uint32_t* Bf = (uint32_t*)d_ws;
        uint4* Ef = (uint4*)((char*)d_ws + bf_bytes);
        uint4* Af = (uint4*)((char*)d_ws + bf_bytes + ef_bytes);
        hipLaunchKernelGGL(pack_trans_frag, dim3((M_ * 8 * 4 * 4 * 64) / 256), dim3(256),
                           0, stream, trans, Bf);
        hipLaunchKernelGGL(pack_emit_frag, dim3((M_ * 8 * 4 * 64) / 256), dim3(256),
                           0, stream, emit, Ef);
        hipLaunchKernelGGL(pack_inputs_frag, dim3((M_ * 4 * L_ * 64) / 256), dim3(256),
                           0, stream, inputs, Af);
        hipLaunchKernelGGL(hmm_fwd_mfma, dim3(M_ * B_ / 16), dim3(NT), 0, stream,
                           init_dist, Bf, Ef, Af, out);
    } else {
        hipLaunchKernelGGL(emission_kernel, dim3(M_ * B_ * (L_ / LB)), dim3(512), 0, stream,
                           inputs, emit, out);
        hipLaunchKernelGGL(hmm_fwd_f32, dim3(M_ * B_), dim3(512), 0, stream,
                           init_dist, trans, out);
    }
}